// Round 9
// baseline (106.298 us; speedup 1.0000x reference)
//
#include <hip/hip_runtime.h>
#include <math.h>

#define NH 192
#define NW 192
#define Wt 193
#define TG 24              // tiles per dim (192/8)
#define NTILE (TG*TG)      // 576
#define TILE_SZ 4096       // 64 j * 64 p
#define TBLK 1536          // table kernel blocks (512 thr each)

// cos(2*pi*num/den) via HW cos (input in revolutions)
__device__ __forceinline__ float cos_rev(float num, float den) {
    float rev = num * __builtin_amdgcn_rcpf(den);
    rev = __builtin_amdgcn_fractf(rev);
    return __builtin_amdgcn_cosf(rev);
}

// ---------------- kernel 1: cos tables only (tiny) ----------------
//   Cz [j][kg][i][r] = cos(2*pi*(kg*4+r)/(i*64+j+2))          (k2 side, float4-packed)
//   CP1[j][k][i]     = cos(2*pi*k/(i*64+j+2)) * P[i][j]       (k1 side, row-packed)
__global__ __launch_bounds__(512) void k_tables(const float* __restrict__ P,
                                                float* __restrict__ Cz,
                                                float* __restrict__ CP1) {
    int idx = blockIdx.x * 512 + threadIdx.x;   // 0..786431
    // Cz entry
    int r  = idx & 3;
    int i  = (idx >> 2) & 63;
    int kg = (idx >> 8) % 48;
    int j  = idx / 12288;
    int k  = kg * 4 + r;
    Cz[idx] = cos_rev((float)k, (float)(i * 64 + j + 2));
    // CP1 entry (different mapping, same flat size)
    int i2 = idx & 63;
    int k2 = (idx >> 6) % 192;
    int j2 = idx / 12288;
    int t2 = i2 * 64 + j2;
    CP1[idx] = cos_rev((float)k2, (float)(t2 + 2)) * P[t2];
}

// ---------------- fused kernel: win + x-GEMM + Nk main loop ----------------
// 576 blocks x 512 thr (8 waves). Block owns one 8x8 (k1,k2) tile = 64 b's.
// Phase B: win (9x9 grid region) -> x[64 j][64 p] GEMM -> private xt region.
// Phase C: R5 main loop — wave w owns k1-row w (8 pairs), lane = i; c2 slice
// LDS-staged per 16-j chunk; c1 coalesced L2; x wave-uniform from (L2-hot) xt.
// LDS union: phase B Ms[4096]+win[4352] floats, phase C cs[2048] float4 —
// the first jc-loop __syncthreads() separates the lifetimes.
__global__ __launch_bounds__(512) void k_fused(const float* __restrict__ grid,
                                               const float* __restrict__ Mw,
                                               const float* __restrict__ Cz,
                                               const float* __restrict__ CP1,
                                               float* __restrict__ xt,
                                               float* __restrict__ out) {
    __shared__ __align__(16) float smem[8448];   // 33792 B
    float* Ms  = smem;                 // [64 j][64 c]
    float* win = smem + 4096;          // [64 p][68] (bank-swizzle pad)
    float4* cs = (float4*)smem;        // [16 jj][2 g][64 i] (phase C alias)

    int bx = blockIdx.x;               // 576; k1g fast -> consecutive blocks share c2
    int k1g = bx % TG, k2g = bx / TG;
    int t = threadIdx.x;

    // ---- phase B: stage M ----
    #pragma unroll
    for (int r = 0; r < 2; ++r) {
        int e = r * 512 + t;
        ((float4*)Ms)[e] = ((const float4*)Mw)[e];
    }
    // window averages: lane = channel c, 8 p's per thread-row
    {
        int c = t & 63, pq = t >> 6;
        const float* gb = grid + ((size_t)(k1g * 8) * Wt + k2g * 8) * 64;
        #pragma unroll
        for (int r = 0; r < 8; ++r) {
            int p = pq * 8 + r;
            int l1 = p >> 3, l2 = p & 7;
            const float* g0 = gb + ((size_t)l1 * Wt + l2) * 64;
            float s = g0[c] + g0[64 + c] + g0[Wt * 64 + c] + g0[Wt * 64 + 64 + c];
            win[p * 68 + c] = 0.25f * s;
        }
    }
    __syncthreads();

    // x[j][p] = sum_c win[p][c] * M[j][c]; lane = p -> coalesced stores
    {
        int p = t & 63, jq = t >> 6;
        float4 wv[16];
        #pragma unroll
        for (int q = 0; q < 16; ++q) wv[q] = *(const float4*)&win[p * 68 + 4 * q];

        float* xb = xt + (size_t)(k1g * TG + k2g) * TILE_SZ;
        #pragma unroll
        for (int r = 0; r < 8; ++r) {
            int j = jq * 8 + r;
            float acc = 0.f;
            #pragma unroll
            for (int q = 0; q < 16; ++q) {
                float4 mv = *(const float4*)&Ms[j * 64 + 4 * q];   // uniform broadcast
                acc += wv[q].x * mv.x + wv[q].y * mv.y + wv[q].z * mv.z + wv[q].w * mv.w;
            }
            xb[(size_t)j * 64 + p] = acc;    // coalesced, lands in local L2
        }
    }

    // ---- phase C: main loop (R5 k_main) ----
    int lane = t & 63;               // i
    int w = __builtin_amdgcn_readfirstlane(t >> 6);   // 0..7 = local l1
    int k1 = k1g * 8 + w;

    const float*  c1p = CP1 + (size_t)k1 * 64 + lane;                    // +12288/j
    const float*  xb2 = xt + (size_t)(k1g * TG + k2g) * TILE_SZ + w * 8; // +64/j (uniform)
    const float4* Cz4 = (const float4*)Cz;
    int kgb = k2g * 2;

    float acc[8];
    #pragma unroll
    for (int l2 = 0; l2 < 8; ++l2) acc[l2] = 0.f;

    for (int jc = 0; jc < 4; ++jc) {
        __syncthreads();             // drains phase-B stores (vmcnt0) / prev chunk
        #pragma unroll
        for (int r = 0; r < 4; ++r) {
            int e = r * 512 + t;     // [0,2048): jj = e>>7, g = (e>>6)&1, i = e&63
            int jj = e >> 7;
            int g  = (e >> 6) & 1;
            int i  = e & 63;
            cs[e] = Cz4[(size_t)((jc * 16 + jj) * 48 + kgb + g) * 64 + i];  // coalesced
        }
        __syncthreads();

        #pragma unroll 4
        for (int jj = 0; jj < 16; ++jj) {
            int j = jc * 16 + jj;
            float  c1 = c1p[(size_t)j * 12288];          // coalesced dword (L2)
            float4 v0 = cs[jj * 128 + lane];             // ds_read_b128, conflict-free
            float4 v1 = cs[jj * 128 + 64 + lane];
            const float4* xj = (const float4*)(xb2 + (size_t)j * 64);  // uniform
            float4 x0 = xj[0];
            float4 x1 = xj[1];
            float c2f[8] = {v0.x, v0.y, v0.z, v0.w, v1.x, v1.y, v1.z, v1.w};
            float xs[8]  = {x0.x, x0.y, x0.z, x0.w, x1.x, x1.y, x1.z, x1.w};
            #pragma unroll
            for (int l2 = 0; l2 < 8; ++l2)
                acc[l2] += xs[l2] * (c1 * c2f[l2]);
        }
    }

    size_t ob = ((size_t)k1 * NW + kgb * 4) * 64 + lane;   // k2g*8 = kgb*4
    #pragma unroll
    for (int l2 = 0; l2 < 8; ++l2)
        out[ob + (size_t)l2 * 64] = acc[l2];  // coalesced dword stores
}

extern "C" void kernel_launch(void* const* d_in, const int* in_sizes, int n_in,
                              void* d_out, int out_size, void* d_ws, size_t ws_size,
                              hipStream_t stream) {
    const float* grid = (const float*)d_in[0];   // [193,193,64]
    const float* Mw   = (const float*)d_in[1];   // [64,64]
    const float* P    = (const float*)d_in[2];   // [64,64]
    float* out = (float*)d_out;                  // [36864,64]

    // ws layout (floats): Cz [786432] | CP1 [786432] | xt [576*4096]
    float* Cz  = (float*)d_ws;
    float* CP1 = Cz + 786432;
    float* xt  = CP1 + 786432;

    k_tables<<<TBLK, 512, 0, stream>>>(P, Cz, CP1);
    k_fused<<<NTILE, 512, 0, stream>>>(grid, Mw, Cz, CP1, xt, out);
}

// Round 10
// 94.952 us; speedup vs baseline: 1.1195x; 1.1195x over previous
//
#include <hip/hip_runtime.h>
#include <math.h>

#define NH 192
#define NW 192
#define Wt 193
#define TG 24              // tiles per dim (192/8)
#define NTILE (TG*TG)      // 576
#define TILE_SZ 4096       // 64 j * 64 p
#define TBLK 3072          // table-builder blocks in fused prep kernel

// cos(2*pi*num/den) via HW cos (input in revolutions)
__device__ __forceinline__ float cos_rev(float num, float den) {
    float rev = num * __builtin_amdgcn_rcpf(den);
    rev = __builtin_amdgcn_fractf(rev);
    return __builtin_amdgcn_cosf(rev);
}

// ---------------- fused prep: tables + x ----------------
// blocks [0,TBLK): build both cos tables (coalesced stores)
//   Cz [j][kg][i][r] = cos(2*pi*(kg*4+r)/(i*64+j+2))          (k2 side, float4-packed)
//   CP1[j][k][i]     = cos(2*pi*k/(i*64+j+2)) * P[i][j]       (k1 side, row-packed)
// blocks [TBLK, TBLK+576): xt[tile][j][p] = (win_avg @ M^T), p = l1*8+l2 local
__global__ __launch_bounds__(256) void k_prep(const float* __restrict__ grid,
                                              const float* __restrict__ Mw,
                                              const float* __restrict__ P,
                                              float* __restrict__ Cz,
                                              float* __restrict__ CP1,
                                              float* __restrict__ xt) {
    __shared__ float Ms[64 * 64];    // M[j][c]
    __shared__ float win[64 * 68];   // win[p][c], stride 68
    int bx = blockIdx.x;
    int t = threadIdx.x;

    if (bx < TBLK) {
        int idx = bx * 256 + t;                 // 0..786431
        // Cz entry
        int r  = idx & 3;
        int i  = (idx >> 2) & 63;
        int kg = (idx >> 8) % 48;
        int j  = idx / 12288;
        int k  = kg * 4 + r;
        Cz[idx] = cos_rev((float)k, (float)(i * 64 + j + 2));
        // CP1 entry (different mapping, same flat size)
        int i2 = idx & 63;
        int k2 = (idx >> 6) % 192;
        int j2 = idx / 12288;
        int t2 = i2 * 64 + j2;
        CP1[idx] = cos_rev((float)k2, (float)(t2 + 2)) * P[t2];
        return;
    }

    int bb = bx - TBLK;                         // 0..575
    int k1g = bb % TG, k2g = bb / TG;

    // stage M (coalesced)
    #pragma unroll
    for (int r = 0; r < 4; ++r) {
        int e = r * 256 + t;
        ((float4*)Ms)[e] = ((const float4*)Mw)[e];
    }

    // window averages: lane = channel c
    {
        int c = t & 63, pq = t >> 6;
        const float* gb = grid + ((size_t)(k1g * 8) * Wt + k2g * 8) * 64;
        #pragma unroll
        for (int r = 0; r < 16; ++r) {
            int p = pq * 16 + r;
            int l1 = p >> 3, l2 = p & 7;
            const float* g0 = gb + ((size_t)l1 * Wt + l2) * 64;
            float s = g0[c] + g0[64 + c] + g0[Wt * 64 + c] + g0[Wt * 64 + 64 + c];
            win[p * 68 + c] = 0.25f * s;
        }
    }
    __syncthreads();

    // x[p][j] = sum_c win[p][c] * M[j][c]; lane = p -> coalesced stores
    int p = t & 63, jq = t >> 6;
    float4 wv[16];
    #pragma unroll
    for (int q = 0; q < 16; ++q) wv[q] = *(const float4*)&win[p * 68 + 4 * q];

    float* xb = xt + (size_t)(k1g * TG + k2g) * TILE_SZ;
    #pragma unroll
    for (int r = 0; r < 16; ++r) {
        int j = jq * 16 + r;
        float acc = 0.f;
        #pragma unroll
        for (int q = 0; q < 16; ++q) {
            float4 mv = *(const float4*)&Ms[j * 64 + 4 * q];   // uniform broadcast
            acc += wv[q].x * mv.x + wv[q].y * mv.y + wv[q].z * mv.z + wv[q].w * mv.w;
        }
        xb[(size_t)j * 64 + p] = acc;    // coalesced
    }
}

// ---------------- k_main: Nk[b,i] ----------------
// 512 thr = 8 waves; tile = 8x8 pairs; wave w owns k1-row w (8 pairs), all 64 j.
// lane = i. c2 slice staged in LDS per 16-j chunk (each float4 fetched ONCE per
// block); c1 per-wave coalesced global (unique); x wave-uniform loads.
__global__ __launch_bounds__(512) void k_main(const float* __restrict__ xt,
                                              const float* __restrict__ Cz,
                                              const float* __restrict__ CP1,
                                              float* __restrict__ out) {
    __shared__ float4 cs[2048];      // 32 KB: [jj(16)][g(2)][i(64)]
    int bx = blockIdx.x;             // 576; consecutive blocks share k2g (c2 slice hot)
    int k1g = bx % TG, k2g = bx / TG;
    int t = threadIdx.x;
    int lane = t & 63;               // i
    int w = __builtin_amdgcn_readfirstlane(t >> 6);   // 0..7 = local l1
    int k1 = k1g * 8 + w;

    const float*  c1p = CP1 + (size_t)k1 * 64 + lane;                    // +12288/j
    const float*  xb  = xt + (size_t)(k1g * TG + k2g) * TILE_SZ + w * 8; // +64/j (uniform)
    const float4* Cz4 = (const float4*)Cz;
    int kgb = k2g * 2;

    float acc[8];
    #pragma unroll
    for (int l2 = 0; l2 < 8; ++l2) acc[l2] = 0.f;

    for (int jc = 0; jc < 4; ++jc) {
        __syncthreads();             // previous chunk fully consumed
        #pragma unroll
        for (int r = 0; r < 4; ++r) {
            int e = r * 512 + t;     // [0,2048): jj = e>>7, g = (e>>6)&1, i = e&63
            int jj = e >> 7;
            int g  = (e >> 6) & 1;
            int i  = e & 63;
            cs[e] = Cz4[(size_t)((jc * 16 + jj) * 48 + kgb + g) * 64 + i];  // coalesced
        }
        __syncthreads();

        #pragma unroll 4
        for (int jj = 0; jj < 16; ++jj) {
            int j = jc * 16 + jj;
            float  c1 = c1p[(size_t)j * 12288];          // coalesced dword (L2)
            float4 v0 = cs[jj * 128 + lane];             // ds_read_b128, conflict-free
            float4 v1 = cs[jj * 128 + 64 + lane];
            const float4* xj = (const float4*)(xb + (size_t)j * 64);  // uniform
            float4 x0 = xj[0];
            float4 x1 = xj[1];
            float c2f[8] = {v0.x, v0.y, v0.z, v0.w, v1.x, v1.y, v1.z, v1.w};
            float xs[8]  = {x0.x, x0.y, x0.z, x0.w, x1.x, x1.y, x1.z, x1.w};
            #pragma unroll
            for (int l2 = 0; l2 < 8; ++l2)
                acc[l2] += xs[l2] * (c1 * c2f[l2]);
        }
    }

    size_t ob = ((size_t)k1 * NW + k2g * 8) * 64 + lane;
    #pragma unroll
    for (int l2 = 0; l2 < 8; ++l2)
        out[ob + (size_t)l2 * 64] = acc[l2];  // coalesced dword stores
}

extern "C" void kernel_launch(void* const* d_in, const int* in_sizes, int n_in,
                              void* d_out, int out_size, void* d_ws, size_t ws_size,
                              hipStream_t stream) {
    const float* grid = (const float*)d_in[0];   // [193,193,64]
    const float* Mw   = (const float*)d_in[1];   // [64,64]
    const float* P    = (const float*)d_in[2];   // [64,64]
    float* out = (float*)d_out;                  // [36864,64]

    // ws layout (floats): Cz [786432] | CP1 [786432] | xt [576*4096]
    float* Cz  = (float*)d_ws;
    float* CP1 = Cz + 786432;
    float* xt  = CP1 + 786432;

    k_prep<<<TBLK + NTILE, 256, 0, stream>>>(grid, Mw, P, Cz, CP1, xt);
    k_main<<<NTILE, 512, 0, stream>>>(xt, Cz, CP1, out);
}